// Round 23
// baseline (21.143 us; speedup 1.0000x reference)
//
#include <hip/hip_runtime.h>

typedef __attribute__((ext_vector_type(8)))  short short8;
typedef __attribute__((ext_vector_type(16))) float f32x16;
typedef __attribute__((ext_vector_type(16))) unsigned u32x16;

#define NPTS 2048
#define BATCH 32
#define NUM_CLASSES 6
#define THREADS 512
// pass1 grid = 32 batches * 4 inst-chunks(512) * 2 model-chunks(1024) = 256
#define BF16_ONE ((short)0x3F80)
#define FMAX_BITS 0x7F7FFFFFu

// ws layout (uint elems):
//   rowpart[32][4][2][512]  at 0        (131072)  per-row partial mins
//   colpart[32][2][4][1024] at 131072   (262144)  per-col partial mins
//   partial[64] floats      at 393216
#define COLPART_OFF 131072
#define PART_OFF    393216

__device__ __forceinline__ unsigned short f2bf(float x) {
    union { float f; unsigned u; } v; v.f = x;
    unsigned r = v.u + 0x7FFF + ((v.u >> 16) & 1);   // RNE to bf16
    return (unsigned short)(r >> 16);
}
__device__ __forceinline__ float bf2f(unsigned short h) {
    union { unsigned u; float f; } v; v.u = ((unsigned)h) << 16; return v.f;
}
__device__ __forceinline__ unsigned f2u(float x) {
    union { float f; unsigned u; } v; v.f = x; return v.u;
}
__device__ __forceinline__ float u2f(unsigned x) {
    union { unsigned u; float f; } v; v.u = x; return v.f;
}
// Distances strictly positive -> uint order == float order (R15-verified).
__device__ __forceinline__ unsigned umin2(unsigned a, unsigned b) {
    return a < b ? a : b;
}
template<int CTRL>
__device__ __forceinline__ unsigned dpp_ror_umin(unsigned v) {
    unsigned r = (unsigned)__builtin_amdgcn_update_dpp((int)v, (int)v, CTRL, 0xF, 0xF, false);
    return umin2(v, r);
}
__device__ __forceinline__ unsigned swz16_umin(unsigned v) {
    unsigned r = (unsigned)__builtin_amdgcn_ds_swizzle((int)v, 0x401F);  // lane^16
    return umin2(v, r);
}

// K-slot plan (K=16), D = a2 + b2 - 2 a.b (absmax-0 verified R3-R22):
//  k0-2: A=ah B=-2bh | k3-5: A=al B=-2bh | k6-8: A=ah B=-2bl
//  k9: A=1 B=b2h | k10: A=1 B=b2l | k11: A=a2h B=1 | k12: A=a2l B=1 | k13-15: 0
// LDS: per 32-cand tile, 1024 B = [32 x kg0][32 x kg1], conflict-free (R13).
// SYMMETRIC (R20 retried without its per-stage GLOBAL atomics): one pass over
// d[inst 512][model 1024] per block; rows -> dist1 partials, cols -> dist2
// partials. Each (wave,col) is produced by exactly ONE tile -> col-min is a
// single ds_write into a per-wave LDS region (no atomics, no init, no rmw).
// Cross-wave combine: LDS tree at block end. Cross-block: reduce kernel.
__global__ __launch_bounds__(THREADS, 2) void chamfer_sym(
    const float* __restrict__ inst, const float* __restrict__ model,
    unsigned* __restrict__ ws)
{
    __shared__ char     cands[1024 * 32];      // 32 KB
    __shared__ unsigned colmin_w[8 * 1024];    // 32 KB, per-wave regions

    const int blk   = blockIdx.x;
    const int batch = blk >> 3;
    const int ic    = (blk >> 1) & 3;          // inst chunk of 512
    const int mc    = blk & 1;                 // model chunk of 1024
    const int tid   = threadIdx.x;
    const int lane  = tid & 63, wid = tid >> 6;   // wid 0..7
    const int lh    = lane >> 5, lr = lane & 31;

    // ---- stage 1024 model cands into tiled B-frag layout (2 per thread) ----
    const float* cb = model + ((size_t)batch * NPTS + (size_t)mc * 1024) * 3;
    #pragma unroll
    for (int k = 0; k < 2; ++k) {
        const int c = tid + k * THREADS;
        float bx = cb[c*3+0], by = cb[c*3+1], bz = cb[c*3+2];
        float m2x = -2.f*bx, m2y = -2.f*by, m2z = -2.f*bz;
        unsigned short hx = f2bf(m2x), hy = f2bf(m2y), hz = f2bf(m2z);
        unsigned short lx = f2bf(m2x - bf2f(hx));
        unsigned short ly = f2bf(m2y - bf2f(hy));
        unsigned short lz = f2bf(m2z - bf2f(hz));
        float b2 = fmaf(bx,bx, fmaf(by,by, bz*bz));
        unsigned short b2h = f2bf(b2);
        unsigned short b2l = f2bf(b2 - bf2f(b2h));
        short8 kg0 = { (short)hx,(short)hy,(short)hz,(short)hx,(short)hy,(short)hz,(short)lx,(short)ly };
        short8 kg1 = { (short)lz,(short)b2h,(short)b2l, BF16_ONE, BF16_ONE, 0,0,0 };
        char* tbase = cands + (c >> 5) * 1024 + (c & 31) * 16;
        *(short8*)(tbase)       = kg0;
        *(short8*)(tbase + 512) = kg1;
    }

    // ---- A-frags: inst rows ic*512 + wid*64 + {0..31, 32..63} ----
    short8 af0, af1;
    const float* qb = inst + ((size_t)batch * NPTS + (size_t)ic * 512) * 3;
    #pragma unroll
    for (int qt = 0; qt < 2; ++qt) {
        const int qi = (wid * 2 + qt) * 32 + lr;
        float x = qb[qi*3+0], y = qb[qi*3+1], z = qb[qi*3+2];
        unsigned short hx = f2bf(x), hy = f2bf(y), hz = f2bf(z);
        unsigned short lx = f2bf(x - bf2f(hx));
        unsigned short ly = f2bf(y - bf2f(hy));
        unsigned short lz = f2bf(z - bf2f(hz));
        float a2 = fmaf(x,x, fmaf(y,y, z*z));
        unsigned short a2h = f2bf(a2);
        unsigned short a2l = f2bf(a2 - bf2f(a2h));
        short8 f;
        if (lh == 0)
            f = (short8){ (short)hx,(short)hy,(short)hz,(short)lx,(short)ly,(short)lz,(short)hx,(short)hy };
        else
            f = (short8){ (short)hz, BF16_ONE, BF16_ONE, (short)a2h,(short)a2l, 0,0,0 };
        if (qt == 0) af0 = f; else af1 = f;
    }
    __syncthreads();

    // ---- pipelined loop: 16 stages x 2 tiles; fold rows AND cols of s-1 ----
    u32x16 mnU, mnU2;
    f32x16 zero16;
    #pragma unroll
    for (int r = 0; r < 16; ++r) { mnU[r] = FMAX_BITS; mnU2[r] = FMAX_BITS; zero16[r] = 0.f; }

    unsigned* myCol = colmin_w + wid * 1024;

    // Fold completed stage results (P00=af0*t0, P01=af0*t1, P10=af1*t0,
    // P11=af1*t1). TB = col base (elems) of tile t0 within this model chunk.
#define FOLD(P00,P01,P10,P11, TB) do {                                         \
    _Pragma("unroll") for (int r = 0; r < 16; ++r)                             \
        mnU[r]  = umin2(umin2(f2u(P00[r]), f2u(P01[r])), mnU[r]);              \
    _Pragma("unroll") for (int r = 0; r < 16; ++r)                             \
        mnU2[r] = umin2(umin2(f2u(P10[r]), f2u(P11[r])), mnU2[r]);             \
    unsigned ca = umin2(f2u(P00[0]), f2u(P10[0]));                             \
    unsigned cc = umin2(f2u(P01[0]), f2u(P11[0]));                             \
    _Pragma("unroll") for (int r = 1; r < 16; ++r) {                           \
        ca = umin2(ca, umin2(f2u(P00[r]), f2u(P10[r])));                       \
        cc = umin2(cc, umin2(f2u(P01[r]), f2u(P11[r])));                       \
    }                                                                          \
    ca = umin2(ca, (unsigned)__shfl_xor((int)ca, 32, 64));                     \
    cc = umin2(cc, (unsigned)__shfl_xor((int)cc, 32, 64));                     \
    if (lh == 0) {                                                             \
        myCol[(TB) + lr]      = ca;                                            \
        myCol[(TB) + 32 + lr] = cc;                                            \
    }                                                                          \
} while (0)

    const char* cp = cands + lh * 512 + lr * 16;
    short8 c0 = *(const short8*)(cp);
    short8 c1 = *(const short8*)(cp + 1024);
    short8 n0 = *(const short8*)(cp + 2048);
    short8 n1 = *(const short8*)(cp + 3072);
    cp += 4096;
    f32x16 p00 = __builtin_amdgcn_mfma_f32_32x32x16_bf16(af0, c0, zero16, 0,0,0);
    f32x16 p01 = __builtin_amdgcn_mfma_f32_32x32x16_bf16(af0, c1, zero16, 0,0,0);
    f32x16 p10 = __builtin_amdgcn_mfma_f32_32x32x16_bf16(af1, c0, zero16, 0,0,0);
    f32x16 p11 = __builtin_amdgcn_mfma_f32_32x32x16_bf16(af1, c1, zero16, 0,0,0);

    #pragma unroll 2
    for (int s = 1; s < 15; ++s) {        // stages 1..14; folds stages 0..13
        c0 = n0; c1 = n1;
        n0 = *(const short8*)(cp);        // prefetch stage s+1
        n1 = *(const short8*)(cp + 1024);
        cp += 2048;
        f32x16 q00 = __builtin_amdgcn_mfma_f32_32x32x16_bf16(af0, c0, zero16, 0,0,0);
        f32x16 q01 = __builtin_amdgcn_mfma_f32_32x32x16_bf16(af0, c1, zero16, 0,0,0);
        f32x16 q10 = __builtin_amdgcn_mfma_f32_32x32x16_bf16(af1, c0, zero16, 0,0,0);
        f32x16 q11 = __builtin_amdgcn_mfma_f32_32x32x16_bf16(af1, c1, zero16, 0,0,0);
        FOLD(p00, p01, p10, p11, (s - 1) * 64);
        p00 = q00; p01 = q01; p10 = q10; p11 = q11;
    }
    {   // stage 15 (tiles 30,31, prefetched in n0/n1) + drain folds
        f32x16 q00 = __builtin_amdgcn_mfma_f32_32x32x16_bf16(af0, n0, zero16, 0,0,0);
        f32x16 q01 = __builtin_amdgcn_mfma_f32_32x32x16_bf16(af0, n1, zero16, 0,0,0);
        f32x16 q10 = __builtin_amdgcn_mfma_f32_32x32x16_bf16(af1, n0, zero16, 0,0,0);
        f32x16 q11 = __builtin_amdgcn_mfma_f32_32x32x16_bf16(af1, n1, zero16, 0,0,0);
        FOLD(p00, p01, p10, p11, 14 * 64);
        FOLD(q00, q01, q10, q11, 15 * 64);
    }
#undef FOLD

    // ---- row epilogue: DPP col-slot reduce -> per-row partial mins ----
    unsigned* rowpart = ws + (((size_t)batch * 4 + ic) * 2 + mc) * 512 + wid * 64;
    #pragma unroll
    for (int r = 0; r < 16; ++r) {
        const int crow = (r & 3) + 8 * (r >> 2) + 4 * lh;
        unsigned v = mnU[r];
        v = dpp_ror_umin<0x121>(v);
        v = dpp_ror_umin<0x122>(v);
        v = dpp_ror_umin<0x124>(v);
        v = dpp_ror_umin<0x128>(v);
        v = swz16_umin(v);
        if (lr == 0) rowpart[crow] = v;
        unsigned w = mnU2[r];
        w = dpp_ror_umin<0x121>(w);
        w = dpp_ror_umin<0x122>(w);
        w = dpp_ror_umin<0x124>(w);
        w = dpp_ror_umin<0x128>(w);
        w = swz16_umin(w);
        if (lr == 0) rowpart[32 + crow] = w;
    }

    // ---- col epilogue: combine 8 wave regions -> per-col partial mins ----
    __syncthreads();
    unsigned* colpart = ws + COLPART_OFF + (((size_t)batch * 2 + mc) * 4 + ic) * 1024;
    #pragma unroll
    for (int k = 0; k < 2; ++k) {
        const int c = tid + k * THREADS;
        unsigned m = colmin_w[c];
        #pragma unroll
        for (int w = 1; w < 8; ++w) m = umin2(m, colmin_w[w * 1024 + c]);
        colpart[c] = m;
    }
}

// ---- kernel 2: combine partials across chunks, sum per (axis,batch) -------
__global__ __launch_bounds__(256) void reduce_kernel(
    const unsigned* __restrict__ ws, float* __restrict__ partial)
{
    const int b     = blockIdx.x & 31;
    const int isCol = blockIdx.x >> 5;
    const int tid   = threadIdx.x;
    float s = 0.f;

    if (isCol == 0) {
        // rows: min over mc pair, sum over 2048 rows of batch b
        #pragma unroll
        for (int k = 0; k < 8; ++k) {
            const int R = k * 256 + tid;
            const int ic = R >> 9, r = R & 511;
            const unsigned* rp = ws + (((size_t)b * 4 + ic) * 2) * 512 + r;
            s += u2f(umin2(rp[0], rp[512]));
        }
    } else {
        // cols: min over 4 ic, sum over 2048 cols of batch b
        #pragma unroll
        for (int k = 0; k < 8; ++k) {
            const int Cq = k * 256 + tid;
            const int mcq = Cq >> 10, c = Cq & 1023;
            const unsigned* cq = ws + COLPART_OFF + (((size_t)b * 2 + mcq) * 4) * 1024 + c;
            unsigned m = umin2(umin2(cq[0], cq[1024]), umin2(cq[2048], cq[3072]));
            s += u2f(m);
        }
    }
    #pragma unroll
    for (int o = 32; o > 0; o >>= 1) s += __shfl_down(s, o, 64);
    __shared__ float wsum[4];
    const int lane = tid & 63, wid = tid >> 6;
    if (lane == 0) wsum[wid] = s;
    __syncthreads();
    if (tid == 0) partial[blockIdx.x] = (wsum[0] + wsum[1]) + (wsum[2] + wsum[3]);
}

// ---- kernel 3: 64-sum + cross-entropy + output -----------------------------
__global__ __launch_bounds__(64) void finalize_kernel(
    const float* __restrict__ partial, const float* __restrict__ pred,
    const int* __restrict__ gt, float* __restrict__ out)
{
    const int tid = threadIdx.x;
    __shared__ float s_ce[BATCH];

    float v = partial[tid];
    #pragma unroll
    for (int o = 32; o > 0; o >>= 1) v += __shfl_down(v, o, 64);

    if (tid < BATCH) {
        const float* row = pred + tid * NUM_CLASSES;
        float mx = row[0];
        #pragma unroll
        for (int c = 1; c < NUM_CLASSES; ++c) mx = fmaxf(mx, row[c]);
        float se = 0.f;
        #pragma unroll
        for (int c = 0; c < NUM_CLASSES; ++c) se += __expf(row[c] - mx);
        const int lbl = gt[tid];
        s_ce[tid] = -(row[lbl] - mx - __logf(se));
    }
    __syncthreads();

    if (tid == 0) {
        float cd = v / (float)(BATCH * NPTS);   // (sum rowmins + colmins)/65536
        float ce = 0.f;
        for (int i = 0; i < BATCH; ++i) ce += s_ce[i];
        ce /= (float)BATCH;
        out[0] = 5.f * cd + ce;
        out[1] = cd;
        out[2] = ce;
    }
}

extern "C" void kernel_launch(void* const* d_in, const int* in_sizes, int n_in,
                              void* d_out, int out_size, void* d_ws, size_t ws_size,
                              hipStream_t stream) {
    const float* inst  = (const float*)d_in[0];
    const float* model = (const float*)d_in[1];
    const float* pred  = (const float*)d_in[2];
    const int*   gt    = (const int*)d_in[3];
    float* out = (float*)d_out;
    unsigned* ws = (unsigned*)d_ws;

    chamfer_sym<<<256, THREADS, 0, stream>>>(inst, model, ws);
    reduce_kernel<<<64, 256, 0, stream>>>(ws, (float*)(ws + PART_OFF));
    finalize_kernel<<<1, 64, 0, stream>>>((float*)(ws + PART_OFF), pred, gt, out);
}